// Round 13
// baseline (108774.646 us; speedup 1.0000x reference)
//
#include <hip/hip_runtime.h>
#include <hip/hip_bf16.h>

#define BZ 4
#define DD 64
#define LL 16384
#define NN 8
#define BLD ((size_t)BZ*DD*LL)     // 4,194,304
#define BML ((size_t)BZ*20*LL)     // 1,310,720

__device__ __forceinline__ float silu_(float x){ return x / (1.f + __expf(-x)); }
__device__ __forceinline__ float softplus_(float x){ return (x > 20.f) ? x : log1pf(__expf(x)); }

// ---------- per-position input stage: LN(a) -> x,z ; LN(e) -> ee -> meta(d=0,1) ----------
__global__ void t_block_in(const float* __restrict__ src0, const float* __restrict__ src1,
                           const float* __restrict__ lng0, const float* __restrict__ lnb0,
                           const float* __restrict__ lng1, const float* __restrict__ lnb1,
                           const float* __restrict__ W_in, const float* __restrict__ W_ine,
                           const float* __restrict__ W_x, int i,
                           float* __restrict__ XB, float* __restrict__ ZB,
                           float* __restrict__ M0, float* __restrict__ M1)
{
  const int gid = blockIdx.x*256 + threadIdx.x;   // [0, BZ*LL)
  const int b = gid >> 14;
  const int l = gid & (LL-1);

  float a[DD], e[DD], ee[DD];

  for (int ch=0; ch<DD; ++ch) a[ch] = src0[((size_t)(b*DD+ch))*LL + l];
  {
    float m=0.f; for (int k=0;k<DD;++k) m += a[k];  m *= (1.f/DD);
    float v=0.f; for (int k=0;k<DD;++k){ float d=a[k]-m; v += d*d; }  v *= (1.f/DD);
    float rs = rsqrtf(v + 1e-5f);
    for (int k=0;k<DD;++k) a[k] = (a[k]-m)*rs*lng0[i*DD+k] + lnb0[i*DD+k];
  }
  for (int ch=0; ch<DD; ++ch) e[ch] = src1[((size_t)(b*DD+ch))*LL + l];
  {
    float m=0.f; for (int k=0;k<DD;++k) m += e[k];  m *= (1.f/DD);
    float v=0.f; for (int k=0;k<DD;++k){ float d=e[k]-m; v += d*d; }  v *= (1.f/DD);
    float rs = rsqrtf(v + 1e-5f);
    for (int k=0;k<DD;++k) e[k] = (e[k]-m)*rs*lng1[i*DD+k] + lnb1[i*DD+k];
  }

  // xz = a @ W_in[i]  (64 x 128); x = first 64 cols, z = last 64
  const float* Wi = W_in + (size_t)i*DD*2*DD;
  for (int j=0; j<2*DD; ++j){
    float s = 0.f;
    for (int k=0;k<DD;++k) s += a[k]*Wi[k*2*DD + j];
    if (j < DD) XB[((size_t)(b*DD+j   ))*LL + l] = s;
    else        ZB[((size_t)(b*DD+j-DD))*LL + l] = s;
  }

  // ee = e @ W_ine[i]  (64 x 64)
  const float* We = W_ine + (size_t)i*DD*DD;
  for (int m2=0; m2<DD; ++m2){
    float s = 0.f;
    for (int k=0;k<DD;++k) s += e[k]*We[k*DD + m2];
    ee[m2] = s;
  }

  // meta[d] = ee @ W_x[i,d]  (64 x 20): cols 0..3 dtr, 4..11 B, 12..19 C
  for (int d=0; d<2; ++d){
    const float* Wx = W_x + ((size_t)(i*2+d)*DD)*20;
    float* M = d ? M1 : M0;
    for (int j=0; j<20; ++j){
      float s = 0.f;
      for (int m2=0; m2<DD; ++m2) s += ee[m2]*Wx[m2*20 + j];
      M[((size_t)(b*20+j))*LL + l] = s;
    }
  }
}

// ---------- serial selective scan (conv+silu on the fly), 1 thread per (b,ch) ----------
// conv: XLA cross-correlation: xc[t] = w0*x[t-3]+w1*x[t-2]+w2*x[t-1]+w3*x[t]
template<int DIR>
__global__ void t_scan(const float* __restrict__ XB, const float* __restrict__ ZB,
                       float* __restrict__ YB, const float* __restrict__ MM,
                       const float* __restrict__ convW, const float* __restrict__ convB,
                       const float* __restrict__ Wdt, const float* __restrict__ bdt,
                       const float* __restrict__ Alog, const float* __restrict__ Dpw, int id)
{
  const int b  = blockIdx.x;     // grid = BZ
  const int ch = threadIdx.x;    // 64

  float cw[4];
  for (int k=0;k<4;++k) cw[k] = convW[((size_t)id*DD+ch)*4 + k];
  const float cb = convB[id*DD + ch];
  float wd[4]; for (int r=0;r<4;++r) wd[r] = Wdt[((size_t)id*4 + r)*DD + ch];
  const float bd = bdt[id*DD + ch];
  float An[NN]; for (int n=0;n<NN;++n) An[n] = -__expf(Alog[((size_t)id*DD+ch)*NN + n]);
  const float dp = Dpw[id*DD + ch];

  const float* xr = XB + ((size_t)(b*DD+ch))*LL;
  const float* zr = ZB + ((size_t)(b*DD+ch))*LL;
  float*       yr = YB + ((size_t)(b*DD+ch))*LL;
  const float* mr = MM + (size_t)b*20*LL;

  float h[NN]; for (int n=0;n<NN;++n) h[n]=0.f;
  float p1=0.f, p2=0.f, p3=0.f;   // x[t-1], x[t-2], x[t-3] in scan order

  for (int s=0; s<LL; ++s){
    const int t = DIR ? (LL-1-s) : s;
    const float xv = xr[t];
    const float xc = silu_(cb + cw[0]*p3 + cw[1]*p2 + cw[2]*p1 + cw[3]*xv);
    p3=p2; p2=p1; p1=xv;

    float dpre = bd;
    for (int r=0;r<4;++r) dpre += mr[(size_t)r*LL + t]*wd[r];
    const float dt = softplus_(dpre);
    const float u = dt*xc;

    float y = 0.f;
    for (int n=0;n<NN;++n){
      const float dA = __expf(dt*An[n]);
      h[n] = h[n]*dA + u*mr[(size_t)(4+n)*LL + t];
      y += h[n]*mr[(size_t)(12+n)*LL + t];
    }
    const float o = (y + xc*dp)*silu_(zr[t]);
    if (DIR) yr[t] += o; else yr[t] = o;
  }
}

// ---------- output stage: y @ W_out + b_out (+ skip) -> dst ----------
__global__ void t_block_out(const float* __restrict__ YB, const float* __restrict__ skip,
                            const float* __restrict__ Wo, const float* __restrict__ bo,
                            float* __restrict__ dst, int mode)
{ // mode 0: dst = r + skip ; 1: dst += r + skip ; 2: dst = r
  const int gid = blockIdx.x*256 + threadIdx.x;
  const int b = gid >> 14;
  const int l = gid & (LL-1);
  float y[DD];
  for (int ch=0; ch<DD; ++ch) y[ch] = YB[((size_t)(b*DD+ch))*LL + l];
  for (int j=0; j<DD; ++j){
    float s = bo[j];
    for (int k=0;k<DD;++k) s += y[k]*Wo[k*DD + j];
    const size_t o = ((size_t)(b*DD+j))*LL + l;
    if (mode != 2) s += skip[o];
    if (mode == 1) dst[o] += s; else dst[o] = s;
  }
}

// ---------- final outputs: d_out is a FLOAT32 buffer (checker reads top16 of each word) ----------
__global__ void t_final(const float* __restrict__ X1, const float* __restrict__ X2,
                        const float* __restrict__ FU, float* __restrict__ o)
{
  const size_t idx = (size_t)blockIdx.x*256 + threadIdx.x;   // logical index in [0, BLD)
  const float f = FU[idx];
  o[idx]       = X1[idx] + f;
  o[BLD + idx] = X2[idx] + f;
}

__global__ void t_pass(const float* __restrict__ s, float* __restrict__ o)
{
  const size_t idx = (size_t)blockIdx.x*256 + threadIdx.x;
  o[idx] = s[idx];
}

extern "C" void kernel_launch(void* const* d_in, const int* in_sizes, int n_in,
                              void* d_out, int out_size, void* d_ws, size_t ws_size,
                              hipStream_t stream)
{
  // ---- input binding: dict order / alphabetical order / generic-by-size ----
  static const int dictsz[21]  = {4194304,4194304,4194304,4194304,256,256,256,256,
                                  32768,16384,2048,512,10240,2048,512,4096,512,
                                  16384,256,4096,64};
  static const int alphasz[21] = {4096,512,2048,4096,32768,16384,16384,10240,512,64,
                                  256,512,2048,4194304,4194304,4194304,4194304,
                                  256,256,256,256};
  int map[21];
  bool okd = (n_in >= 21), oka = (n_in >= 21);
  for (int i=0; i<21; ++i){
    if (okd && in_sizes[i] != dictsz[i])  okd = false;
    if (oka && in_sizes[i] != alphasz[i]) oka = false;
  }
  if (okd){
    for (int i=0;i<21;++i) map[i] = i;
  } else if (oka){
    static const int am[21] = {13,15,14,16,19,17,20,18,4,5,12,11,7,2,8,0,1,6,10,3,9};
    for (int i=0;i<21;++i) map[i] = am[i];
  } else {
    bool used[64];
    for (int j=0;j<64;++j) used[j]=false;
    for (int i=0;i<21;++i){
      map[i] = -1;
      for (int j=0;j<n_in && j<64;++j)
        if (!used[j] && in_sizes[j]==dictsz[i]){ map[i]=j; used[j]=true; break; }
      if (map[i] < 0) map[i] = (i < n_in ? i : 0);
    }
  }

  const float* img1 = (const float*)d_in[map[0]];
  const float* img2 = (const float*)d_in[map[1]];
  const float* s1   = (const float*)d_in[map[2]];
  const float* s2   = (const float*)d_in[map[3]];
  const float* lng0 = (const float*)d_in[map[4]];
  const float* lnb0 = (const float*)d_in[map[5]];
  const float* lng1 = (const float*)d_in[map[6]];
  const float* lnb1 = (const float*)d_in[map[7]];
  const float* Win  = (const float*)d_in[map[8]];
  const float* Wine = (const float*)d_in[map[9]];
  const float* convW= (const float*)d_in[map[10]];
  const float* convB= (const float*)d_in[map[11]];
  const float* Wx   = (const float*)d_in[map[12]];
  const float* Wdt  = (const float*)d_in[map[13]];
  const float* bdt  = (const float*)d_in[map[14]];
  const float* Alog = (const float*)d_in[map[15]];
  const float* Dp   = (const float*)d_in[map[16]];
  const float* Wout = (const float*)d_in[map[17]];
  const float* bout = (const float*)d_in[map[18]];
  const float* Wfo  = (const float*)d_in[map[19]];
  const float* bfo  = (const float*)d_in[map[20]];

  float* ob = (float*)d_out;    // f32 output buffer (checker extracts top 16 bits per word)

  float* ws = (float*)d_ws;
  float* X1 = ws;
  float* X2 = ws + 1*BLD;
  float* FS = ws + 2*BLD;
  float* XB = ws + 3*BLD;   // reused as FU at the end
  float* ZB = ws + 4*BLD;
  float* YB = ws + 5*BLD;
  float* M0 = ws + 6*BLD;
  float* M1 = M0 + BML;

  // pass-through outputs 2/3
  t_pass<<<16384,256,0,stream>>>(s1, ob + 2*BLD);
  t_pass<<<16384,256,0,stream>>>(s2, ob + 3*BLD);

  const size_t need = (6*BLD + 2*BML + 64)*sizeof(float);
  if (ws_size < need) return;

  const float* bx0[4] = {img1, img2, X1, X2};
  const float* bx1[4] = {s1,   s2,   X2, X1};
  float*       bdst[4]= {X1,   X2,   FS, FS};
  const int    bmode[4]= {0, 0, 0, 1};

  for (int i=0; i<4; ++i){
    t_block_in<<<256,256,0,stream>>>(bx0[i], bx1[i], lng0, lnb0, lng1, lnb1,
                                     Win, Wine, Wx, i, XB, ZB, M0, M1);
    t_scan<0><<<BZ,64,0,stream>>>(XB, ZB, YB, M0, convW, convB, Wdt, bdt, Alog, Dp, i*2+0);
    t_scan<1><<<BZ,64,0,stream>>>(XB, ZB, YB, M1, convW, convB, Wdt, bdt, Alog, Dp, i*2+1);
    t_block_out<<<256,256,0,stream>>>(YB, bx0[i], Wout + (size_t)i*DD*DD, bout + i*DD,
                                      bdst[i], bmode[i]);
  }

  // fusion = FS @ W_fo + b_fo -> XB (reused as FU)
  t_block_out<<<256,256,0,stream>>>(FS, nullptr, Wfo, bfo, XB, 2);
  t_final<<<16384,256,0,stream>>>(X1, X2, XB, ob);
}

// Round 14
// 1742.283 us; speedup vs baseline: 62.4323x; 62.4323x over previous
//
#include <hip/hip_runtime.h>
#include <hip/hip_bf16.h>

#define BZ 4
#define DD 64
#define LL 16384
#define NN 8
#define NC_ 256
#define TCH 64                      // LL / NC_
#define BLD ((size_t)BZ*DD*LL)      // 4,194,304
#define BML ((size_t)BZ*20*LL)      // 1,310,720
#define SCN ((size_t)BZ*NC_*DD*NN)  // 524,288

__device__ __forceinline__ float silu_(float x){ return x / (1.f + __expf(-x)); }
__device__ __forceinline__ float softplus_(float x){ return (x > 20.f) ? x : log1pf(__expf(x)); }

// ---------- input stage: LN(a)->x,z (B,L,D); LN(e)->ee->meta (B,L,20) ----------
// src0, src1 are channel-major (B,D,L); reads coalesced across threads (consecutive l).
__global__ __launch_bounds__(256)
void k_in(const float* __restrict__ src0, const float* __restrict__ src1,
          const float* __restrict__ lng0, const float* __restrict__ lnb0,
          const float* __restrict__ lng1, const float* __restrict__ lnb1,
          const float* __restrict__ W_in, const float* __restrict__ W_ine,
          const float* __restrict__ W_x, int i,
          float* __restrict__ XB, float* __restrict__ ZB,
          float* __restrict__ M0, float* __restrict__ M1)
{
  const int gid = blockIdx.x*256 + threadIdx.x;   // [0, BZ*LL)
  const int b = gid >> 14;
  const int l = gid & (LL-1);

  float a[DD];
  for (int ch=0; ch<DD; ++ch) a[ch] = src0[((size_t)(b*DD+ch))*LL + l];
  {
    float m=0.f; for (int k=0;k<DD;++k) m += a[k];  m *= (1.f/DD);
    float v=0.f; for (int k=0;k<DD;++k){ float d=a[k]-m; v += d*d; }  v *= (1.f/DD);
    float rs = rsqrtf(v + 1e-5f);
    for (int k=0;k<DD;++k) a[k] = (a[k]-m)*rs*lng0[i*DD+k] + lnb0[i*DD+k];
  }

  // xz = a @ W_in[i] (64x128): groups of 16 columns, float4 stores to (B,L,D)
  const float* Wi = W_in + (size_t)i*DD*2*DD;
  float* xrow = XB + ((size_t)b*LL + l)*DD;
  float* zrow = ZB + ((size_t)b*LL + l)*DD;
  for (int g=0; g<8; ++g){
    float acc[16];
    #pragma unroll
    for (int j=0;j<16;++j) acc[j]=0.f;
    for (int k=0;k<DD;++k){
      const float av = a[k];
      const float* wr = Wi + k*128 + g*16;
      #pragma unroll
      for (int j=0;j<16;++j) acc[j] = fmaf(av, wr[j], acc[j]);
    }
    float* drow = (g<4) ? (xrow + g*16) : (zrow + (g-4)*16);
    #pragma unroll
    for (int q=0;q<4;++q)
      ((float4*)drow)[q] = make_float4(acc[4*q],acc[4*q+1],acc[4*q+2],acc[4*q+3]);
  }

  // e path
  float e[DD], ee[DD];
  for (int ch=0; ch<DD; ++ch) e[ch] = src1[((size_t)(b*DD+ch))*LL + l];
  {
    float m=0.f; for (int k=0;k<DD;++k) m += e[k];  m *= (1.f/DD);
    float v=0.f; for (int k=0;k<DD;++k){ float d=e[k]-m; v += d*d; }  v *= (1.f/DD);
    float rs = rsqrtf(v + 1e-5f);
    for (int k=0;k<DD;++k) e[k] = (e[k]-m)*rs*lng1[i*DD+k] + lnb1[i*DD+k];
  }
  const float* We = W_ine + (size_t)i*DD*DD;
  for (int m2=0; m2<DD; ++m2){
    float s = 0.f;
    for (int k=0;k<DD;++k) s = fmaf(e[k], We[k*DD + m2], s);
    ee[m2] = s;
  }
  for (int d=0; d<2; ++d){
    float acc[20];
    #pragma unroll
    for (int j=0;j<20;++j) acc[j]=0.f;
    for (int m2=0; m2<DD; ++m2){
      const float ev = ee[m2];
      const float* wr = W_x + ((size_t)(i*2+d)*DD + m2)*20;
      #pragma unroll
      for (int j=0;j<20;++j) acc[j] = fmaf(ev, wr[j], acc[j]);
    }
    float* mrow = (d ? M1 : M0) + ((size_t)b*LL + l)*20;
    #pragma unroll
    for (int q=0;q<5;++q)
      ((float4*)mrow)[q] = make_float4(acc[4*q],acc[4*q+1],acc[4*q+2],acc[4*q+3]);
  }
}

// ---------- chunked selective scan; conv+silu on the fly ----------
// PASSC=false: per-chunk P (decay product) and F (local end state), h0=0.
// PASSC=true : re-run with Hin as incoming state, emit y.
template<int DIR, bool PASSC>
__global__ __launch_bounds__(64)
void k_scan(const float* __restrict__ xb, const float* __restrict__ zb,
            float* __restrict__ yb, const float* __restrict__ meta,
            const float* __restrict__ convW, const float* __restrict__ convB,
            const float* __restrict__ Wdt, const float* __restrict__ bdt,
            const float* __restrict__ Alog, const float* __restrict__ Dpw, int id,
            float* __restrict__ Pb, float* __restrict__ Fb,
            const float* __restrict__ Hin)
{
  const int ch = threadIdx.x;          // 64
  const int c  = blockIdx.x & (NC_-1);
  const int b  = blockIdx.x >> 8;

  float cw[4];
  for (int k=0;k<4;++k) cw[k] = convW[((size_t)id*DD+ch)*4 + k];
  const float cb = convB[id*DD + ch];
  float wd[4]; for (int r=0;r<4;++r) wd[r] = Wdt[((size_t)id*4 + r)*DD + ch];
  const float bd = bdt[id*DD + ch];
  float An[NN]; for (int n=0;n<NN;++n) An[n] = -__expf(Alog[((size_t)id*DD+ch)*NN + n]);
  const float dp = PASSC ? Dpw[id*DD + ch] : 0.f;

  const size_t sbase = ((size_t)(b*NC_+c)*DD + ch)*NN;
  float h[NN], P[NN];
  if (PASSC){
    #pragma unroll
    for (int n=0;n<NN;++n) h[n] = Hin[sbase+n];
  } else {
    #pragma unroll
    for (int n=0;n<NN;++n){ h[n]=0.f; P[n]=1.f; }
  }

  int t0, stp;
  if (DIR==0){ t0 = c*TCH;        stp =  1; }
  else       { t0 = LL-1 - c*TCH; stp = -1; }

  // prime conv window from neighboring chunk (in scan order)
  float p1=0.f, p2=0.f, p3=0.f;
  {
    int tp = t0 - stp;
    if ((unsigned)tp < LL) p1 = xb[((size_t)b*LL+tp)*DD+ch];
    tp -= stp;
    if ((unsigned)tp < LL) p2 = xb[((size_t)b*LL+tp)*DD+ch];
    tp -= stp;
    if ((unsigned)tp < LL) p3 = xb[((size_t)b*LL+tp)*DD+ch];
  }

  int t = t0;
  for (int s=0; s<TCH; ++s, t+=stp){
    const size_t row = (size_t)b*LL + t;
    const float xv = xb[row*DD+ch];
    const float xc = silu_(cb + cw[0]*p3 + cw[1]*p2 + cw[2]*p1 + cw[3]*xv);
    p3=p2; p2=p1; p1=xv;

    const float* mt = meta + row*20;
    const float dpre = bd + mt[0]*wd[0] + mt[1]*wd[1] + mt[2]*wd[2] + mt[3]*wd[3];
    const float dt = softplus_(dpre);
    const float u = dt*xc;

    if (!PASSC){
      #pragma unroll
      for (int n=0;n<NN;++n){
        const float dA = __expf(dt*An[n]);
        h[n] = h[n]*dA + u*mt[4+n];
        P[n] *= dA;
      }
    } else {
      float y = 0.f;
      #pragma unroll
      for (int n=0;n<NN;++n){
        const float dA = __expf(dt*An[n]);
        h[n] = h[n]*dA + u*mt[4+n];
        y = fmaf(h[n], mt[12+n], y);
      }
      const float zv = zb[row*DD+ch];
      const float o = (y + xc*dp)*silu_(zv);
      float* yp = yb + row*DD + ch;
      if (DIR==0) *yp = o; else *yp += o;
    }
  }

  if (!PASSC){
    #pragma unroll
    for (int n=0;n<NN;++n){ Pb[sbase+n] = P[n]; Fb[sbase+n] = h[n]; }
  }
}

// ---------- inter-chunk state propagation: h_in[c] for each (b, ch, n) ----------
__global__ __launch_bounds__(256)
void k_mid(const float* __restrict__ Pb, const float* __restrict__ Fb,
           float* __restrict__ Hin)
{
  const int idx = blockIdx.x*256 + threadIdx.x;  // [0, BZ*DD*NN) = 2048
  const int b  = idx >> 9;
  const int cn = idx & 511;
  float h = 0.f;
  #pragma unroll 4
  for (int c=0; c<NC_; ++c){
    const size_t a2 = (((size_t)(b*NC_+c))<<9) + cn;
    Hin[a2] = h;
    h = h*Pb[a2] + Fb[a2];
  }
}

// ---------- output stage: y(B,L,D) @ W_out + b_out + skip(B,D,L) -> dst(B,D,L) ----------
template<int MODE>   // 0: dst = r + skip ; 1: dst += r + skip
__global__ __launch_bounds__(256)
void k_out(const float* __restrict__ YB, const float* __restrict__ skip,
           const float* __restrict__ Wo, const float* __restrict__ bo,
           float* __restrict__ dst)
{
  const int gid = blockIdx.x*256 + threadIdx.x;
  const int b = gid >> 14;
  const int l = gid & (LL-1);
  float y[DD];
  {
    const float4* s4 = (const float4*)(YB + ((size_t)b*LL + l)*DD);
    #pragma unroll
    for (int q=0;q<16;++q){ float4 v=s4[q]; y[4*q]=v.x; y[4*q+1]=v.y; y[4*q+2]=v.z; y[4*q+3]=v.w; }
  }
  for (int g=0; g<4; ++g){
    float acc[16];
    #pragma unroll
    for (int j=0;j<16;++j) acc[j]=0.f;
    for (int k=0;k<DD;++k){
      const float av = y[k];
      const float* wr = Wo + k*DD + g*16;
      #pragma unroll
      for (int j=0;j<16;++j) acc[j] = fmaf(av, wr[j], acc[j]);
    }
    #pragma unroll
    for (int j=0;j<16;++j){
      const int col = g*16 + j;
      const size_t o = ((size_t)(b*DD+col))*LL + l;
      float s = acc[j] + bo[col] + skip[o];
      if (MODE==1) s += dst[o];
      dst[o] = s;
    }
  }
}

// ---------- fused final: FU = FS@W_fo + b_fo; out0 = X1+FU; out1 = X2+FU ----------
__global__ __launch_bounds__(256)
void k_fuse(const float* __restrict__ FS, const float* __restrict__ X1,
            const float* __restrict__ X2, const float* __restrict__ Wfo,
            const float* __restrict__ bfo, float* __restrict__ ob)
{
  const int gid = blockIdx.x*256 + threadIdx.x;
  const int b = gid >> 14;
  const int l = gid & (LL-1);
  float fs[DD];
  for (int ch=0; ch<DD; ++ch) fs[ch] = FS[((size_t)(b*DD+ch))*LL + l];
  for (int g=0; g<4; ++g){
    float acc[16];
    #pragma unroll
    for (int j=0;j<16;++j) acc[j]=0.f;
    for (int k=0;k<DD;++k){
      const float av = fs[k];
      const float* wr = Wfo + k*DD + g*16;
      #pragma unroll
      for (int j=0;j<16;++j) acc[j] = fmaf(av, wr[j], acc[j]);
    }
    #pragma unroll
    for (int j=0;j<16;++j){
      const int col = g*16 + j;
      const size_t o = ((size_t)(b*DD+col))*LL + l;
      const float fu = acc[j] + bfo[col];
      ob[o]       = X1[o] + fu;
      ob[BLD + o] = X2[o] + fu;
    }
  }
}

__global__ __launch_bounds__(256)
void k_copy4(const float* __restrict__ s, float* __restrict__ o)
{
  const size_t i = (size_t)blockIdx.x*256 + threadIdx.x;
  ((float4*)o)[i] = ((const float4*)s)[i];
}

extern "C" void kernel_launch(void* const* d_in, const int* in_sizes, int n_in,
                              void* d_out, int out_size, void* d_ws, size_t ws_size,
                              hipStream_t stream)
{
  // ---- input binding (dict order verified in R13; keep fallback) ----
  static const int dictsz[21]  = {4194304,4194304,4194304,4194304,256,256,256,256,
                                  32768,16384,2048,512,10240,2048,512,4096,512,
                                  16384,256,4096,64};
  int map[21];
  bool okd = (n_in >= 21);
  if (okd) for (int i=0;i<21;++i) if (in_sizes[i] != dictsz[i]) { okd = false; break; }
  if (okd){
    for (int i=0;i<21;++i) map[i] = i;
  } else {
    bool used[64];
    for (int j=0;j<64;++j) used[j]=false;
    for (int i=0;i<21;++i){
      map[i] = -1;
      for (int j=0;j<n_in && j<64;++j)
        if (!used[j] && in_sizes[j]==dictsz[i]){ map[i]=j; used[j]=true; break; }
      if (map[i] < 0) map[i] = (i < n_in ? i : 0);
    }
  }

  const float* img1 = (const float*)d_in[map[0]];
  const float* img2 = (const float*)d_in[map[1]];
  const float* s1   = (const float*)d_in[map[2]];
  const float* s2   = (const float*)d_in[map[3]];
  const float* lng0 = (const float*)d_in[map[4]];
  const float* lnb0 = (const float*)d_in[map[5]];
  const float* lng1 = (const float*)d_in[map[6]];
  const float* lnb1 = (const float*)d_in[map[7]];
  const float* Win  = (const float*)d_in[map[8]];
  const float* Wine = (const float*)d_in[map[9]];
  const float* convW= (const float*)d_in[map[10]];
  const float* convB= (const float*)d_in[map[11]];
  const float* Wx   = (const float*)d_in[map[12]];
  const float* Wdt  = (const float*)d_in[map[13]];
  const float* bdt  = (const float*)d_in[map[14]];
  const float* Alog = (const float*)d_in[map[15]];
  const float* Dp   = (const float*)d_in[map[16]];
  const float* Wout = (const float*)d_in[map[17]];
  const float* bout = (const float*)d_in[map[18]];
  const float* Wfo  = (const float*)d_in[map[19]];
  const float* bfo  = (const float*)d_in[map[20]];

  float* ob = (float*)d_out;   // f32 output buffer (checker reads top 16 bits per word)

  float* ws = (float*)d_ws;
  float* X1 = ws;               // (B,D,L)
  float* X2 = ws + 1*BLD;       // (B,D,L)
  float* FS = ws + 2*BLD;       // (B,D,L)
  float* XB = ws + 3*BLD;       // (B,L,D)
  float* ZB = ws + 4*BLD;       // (B,L,D)
  float* YB = ws + 5*BLD;       // (B,L,D)
  float* M0 = ws + 6*BLD;       // (B,L,20)
  float* M1 = M0 + BML;
  float* PP = M1 + BML;
  float* FF = PP + SCN;
  float* HH = FF + SCN;

  // pass-through outputs 2/3
  k_copy4<<<4096,256,0,stream>>>(s1, ob + 2*BLD);
  k_copy4<<<4096,256,0,stream>>>(s2, ob + 3*BLD);

  const size_t need = (6*BLD + 2*BML + 3*SCN + 64)*sizeof(float);
  if (ws_size < need) return;

  const float* bx0[4] = {img1, img2, X1, X2};
  const float* bx1[4] = {s1,   s2,   X2, X1};

  for (int i=0; i<4; ++i){
    k_in<<<256,256,0,stream>>>(bx0[i], bx1[i], lng0, lnb0, lng1, lnb1,
                               Win, Wine, Wx, i, XB, ZB, M0, M1);
    for (int d=0; d<2; ++d){
      const int id = i*2+d;
      const float* Md = d ? M1 : M0;
      if (d==0){
        k_scan<0,false><<<BZ*NC_,64,0,stream>>>(XB,nullptr,nullptr,Md,convW,convB,Wdt,bdt,Alog,nullptr,id,PP,FF,nullptr);
        k_mid<<<8,256,0,stream>>>(PP,FF,HH);
        k_scan<0,true ><<<BZ*NC_,64,0,stream>>>(XB,ZB,YB,Md,convW,convB,Wdt,bdt,Alog,Dp,id,nullptr,nullptr,HH);
      } else {
        k_scan<1,false><<<BZ*NC_,64,0,stream>>>(XB,nullptr,nullptr,Md,convW,convB,Wdt,bdt,Alog,nullptr,id,PP,FF,nullptr);
        k_mid<<<8,256,0,stream>>>(PP,FF,HH);
        k_scan<1,true ><<<BZ*NC_,64,0,stream>>>(XB,ZB,YB,Md,convW,convB,Wdt,bdt,Alog,Dp,id,nullptr,nullptr,HH);
      }
    }
    const float* Wop = Wout + (size_t)i*DD*DD;
    const float* bop = bout + (size_t)i*DD;
    if      (i==0) k_out<0><<<256,256,0,stream>>>(YB, img1, Wop, bop, X1);
    else if (i==1) k_out<0><<<256,256,0,stream>>>(YB, img2, Wop, bop, X2);
    else if (i==2) k_out<0><<<256,256,0,stream>>>(YB, X1,   Wop, bop, FS);
    else           k_out<1><<<256,256,0,stream>>>(YB, X2,   Wop, bop, FS);
  }

  k_fuse<<<256,256,0,stream>>>(FS, X1, X2, Wfo, bfo, ob);
}